// Round 11
// baseline (192.688 us; speedup 1.0000x reference)
//
#include <hip/hip_runtime.h>
#include <hip/hip_bf16.h>
#include <hip/hip_fp16.h>

// Problem constants (match reference)
#define CUTOFF_C    12.0f
#define CUTOFF_SR_C 2.0f
#define CUTOFF_SQ_C 144.0f
#define KEHALF_C    7.199822675975274f

// chunk = 33792 atoms -> 132 KB LDS (half2 accumulator), 1 block/CU
#define CH_T0  33792
#define S1_N   252     // kernel-1 slices (also its grid); 252 % 4 == 0
#define BLK1   1024
#define BLK2   1024

__device__ __forceinline__ float edge_energy(float d, float qi, float qj,
                                             float di, float dj) {
    float inv_d   = __frcp_rn(d);
    float dsh     = __fsqrt_rn(fmaf(d, d, 1.0f));
    float inv_dsh = __frcp_rn(dsh);
    float x  = d * (1.0f / CUTOFF_SR_C);
    float x3 = x * x * x;
    float sw = fmaf(x3, fmaf(x, fmaf(x, -6.0f, 15.0f), -10.0f), 1.0f);
    float sw_off = (d < CUTOFF_SR_C) ? sw : 0.0f;
    float Eoq = inv_d   + fmaf(d,   (1.0f / CUTOFF_SQ_C), -(2.0f / CUTOFF_C));
    float Esq = inv_dsh + fmaf(dsh, (1.0f / CUTOFF_SQ_C), -(2.0f / CUTOFF_C));
    float Eq  = (KEHALF_C * qi * qj) * fmaf(sw_off, Esq - Eoq, Eoq);
    float Eod = inv_d * inv_d * inv_d;
    float Esd = inv_dsh * inv_dsh * inv_dsh;
    float Ed  = (KEHALF_C * di * dj) * fmaf(sw_off, Esd - Eod, Eod);
    return Eq + Ed;
}

// v = KEHALF*qj*F(d), w = KEHALF*dj*G(d); out[i] = qi*sum(v) + di*sum(w)
// (recombination in the reduce with exact fp32 q/dip).
__device__ __forceinline__ __half2 vw_make(float d, __half2 hqdj) {
    float2 qdj    = __half22float2(hqdj);
    float inv_d   = __frcp_rn(d);
    float dsh     = __fsqrt_rn(fmaf(d, d, 1.0f));
    float inv_dsh = __frcp_rn(dsh);
    float x  = d * (1.0f / CUTOFF_SR_C);
    float x3 = x * x * x;
    float sw = fmaf(x3, fmaf(x, fmaf(x, -6.0f, 15.0f), -10.0f), 1.0f);
    float sw_off = (d < CUTOFF_SR_C) ? sw : 0.0f;
    float Foq = inv_d   + fmaf(d,   (1.0f / CUTOFF_SQ_C), -(2.0f / CUTOFF_C));
    float Fsq = inv_dsh + fmaf(dsh, (1.0f / CUTOFF_SQ_C), -(2.0f / CUTOFF_C));
    float F   = fmaf(sw_off, Fsq - Foq, Foq);
    float God = inv_d * inv_d * inv_d;
    float Gsd = inv_dsh * inv_dsh * inv_dsh;
    float G   = fmaf(sw_off, Gsd - God, God);
    return __floats2half2_rn(KEHALF_C * qdj.x * F, KEHALF_C * qdj.y * G);
}

__device__ __forceinline__ unsigned h2bits(__half2 h) {
    union { __half2 h; unsigned u; } c; c.h = h; return c.u;
}
__device__ __forceinline__ __half2 bits2h(unsigned u) {
    union { unsigned u; __half2 h; } c; c.u = u; return c.h;
}
// half2 atomic add: HW atomicAdd(__half2*) if available, else CAS.
template <typename T>
__device__ __forceinline__ auto atom_add_h2(T* p, T v, int)
    -> decltype(atomicAdd(p, v), void()) {
    atomicAdd(p, v);
}
template <typename T>
__device__ __forceinline__ void atom_add_h2(T* p, T v, long) {
    unsigned* u = (unsigned*)p;
    unsigned old = *u, assumed;
    do {
        assumed = old;
        __half2 sum = __hadd2(bits2h(assumed), v);
        old = atomicCAS(u, assumed, h2bits(sum));
    } while (old != assumed);
}

// Pack {q, dip} -> half2 (4 B / atom), j-side gather table.
__global__ __launch_bounds__(256) void pc_pack_qd_h(
    const float* __restrict__ q,
    const float* __restrict__ dip,
    __half2*     __restrict__ qd,
    int n_atoms)
{
    int a = blockIdx.x * 256 + threadIdx.x;
    if (a < n_atoms) qd[a] = __floats2half2_rn(q[a], dip[a]);
}

// Kernel 1 (producer + chunk-0 scatter): block s streams slice s of
// (dist, idx_i, idx_j) ONCE; computes vw for ALL survivors at ~88% lane
// efficiency (all 5.66M qd[j] gathers happen here, at the gather-rate
// ceiling); writes vw[e] (vectored); ds_adds survivors with i < CH into
// the 132 KB LDS half2 accumulator. Grid = S1 = 252 (<= 256, no tail).
template <int CH>
__global__ __launch_bounds__(BLK1) void pc_produce_scatter0(
    const float*   __restrict__ dist,
    const int*     __restrict__ idx_i,
    const int*     __restrict__ idx_j,
    const __half2* __restrict__ qd,
    __half2*       __restrict__ vw,        // [n_edges]
    __half2*       __restrict__ partial0,  // [S1][CH]
    int n_edges, int n4, int S1, int gps)
{
    extern __shared__ __half2 acc2[];      // CH half2

    const int s = blockIdx.x;
    const __half2 hzero = __floats2half2_rn(0.0f, 0.0f);
    for (int i = threadIdx.x; i < CH; i += BLK1) acc2[i] = hzero;
    __syncthreads();

    const int g0 = s * gps;
    const int g1 = min(g0 + gps, n4);
    const int4*   idxi4 = (const int4*)idx_i;
    const int4*   idxj4 = (const int4*)idx_j;
    const float4* dist4 = (const float4*)dist;

    for (int g = g0 + (int)threadIdx.x; g < g1; g += BLK1) {
        int4   j4 = idxj4[g];
        float4 d4 = dist4[g];
        int4   i4 = idxi4[g];

        int   jj[4] = { j4.x, j4.y, j4.z, j4.w };
        int   ii[4] = { i4.x, i4.y, i4.z, i4.w };
        float dd[4] = { d4.x, d4.y, d4.z, d4.w };
        bool  sv[4];
        __half2 qh[4];

        #pragma unroll
        for (int k = 0; k < 4; ++k) sv[k] = (dd[k] <= CUTOFF_C);
        // all 4 gathers in flight before first use
        #pragma unroll
        for (int k = 0; k < 4; ++k) qh[k] = sv[k] ? qd[jj[k]] : hzero;

        __half2 vwv[4];
        #pragma unroll
        for (int k = 0; k < 4; ++k)
            vwv[k] = sv[k] ? vw_make(dd[k], qh[k]) : hzero;

        uint4 st;
        st.x = h2bits(vwv[0]); st.y = h2bits(vwv[1]);
        st.z = h2bits(vwv[2]); st.w = h2bits(vwv[3]);
        ((uint4*)vw)[g] = st;

        #pragma unroll
        for (int k = 0; k < 4; ++k) {
            unsigned lc = (unsigned)ii[k];
            if (sv[k] && lc < (unsigned)CH)
                atom_add_h2(&acc2[lc], vwv[k], 0);
        }
    }

    if (s == S1 - 1) {  // scalar tail (n_edges % 4)
        for (int e = (n4 << 2) + (int)threadIdx.x; e < n_edges; e += BLK1) {
            float d = dist[e];
            __half2 r = hzero;
            if (d <= CUTOFF_C) r = vw_make(d, qd[idx_j[e]]);
            vw[e] = r;
            unsigned lc = (unsigned)idx_i[e];
            if (d <= CUTOFF_C && lc < (unsigned)CH)
                atom_add_h2(&acc2[lc], r, 0);
        }
    }

    __syncthreads();
    __half2* row = partial0 + (size_t)s * CH;
    for (int i = threadIdx.x; i < CH; i += BLK1) row[i] = acc2[i];
}

// Kernel 2 (light passes, chunks 1..nch-1): block (s, c) streams slice s of
// (idx_i, vw) — 8 B/edge, NO gathers, NO transcendentals — and ds_adds
// survivors of chunk c. Grid = S2 * (nch-1) (= 256 for nch=3).
template <int CH>
__global__ __launch_bounds__(BLK2) void pc_scatter_rest(
    const int*     __restrict__ idx_i,
    const __half2* __restrict__ vw,
    __half2*       __restrict__ partial12, // [nch-1][S2][CH]
    int n_edges, int n4, int S2, int gps, int nrest)
{
    extern __shared__ __half2 acc2[];      // CH half2

    const int cr   = blockIdx.x % nrest;   // 0..nrest-1 -> chunk cr+1
    const int s    = blockIdx.x / nrest;
    const int base = (cr + 1) * CH;

    const __half2 hzero = __floats2half2_rn(0.0f, 0.0f);
    for (int i = threadIdx.x; i < CH; i += BLK2) acc2[i] = hzero;
    __syncthreads();

    const int g0 = s * gps;
    const int g1 = min(g0 + gps, n4);
    const int4*  idxi4 = (const int4*)idx_i;
    const uint4* vw4   = (const uint4*)vw;

    for (int g = g0 + (int)threadIdx.x; g < g1; g += BLK2) {
        int4  i4 = idxi4[g];
        uint4 u4 = vw4[g];
        int      ii[4] = { i4.x, i4.y, i4.z, i4.w };
        unsigned uu[4] = { u4.x, u4.y, u4.z, u4.w };
        #pragma unroll
        for (int k = 0; k < 4; ++k) {
            unsigned lc = (unsigned)(ii[k] - base);
            if (lc < (unsigned)CH && uu[k] != 0u)
                atom_add_h2(&acc2[lc], bits2h(uu[k]), 0);
        }
    }

    if (s == S2 - 1) {  // scalar tail
        for (int e = (n4 << 2) + (int)threadIdx.x; e < n_edges; e += BLK2) {
            unsigned lc = (unsigned)(idx_i[e] - base);
            __half2 r = vw[e];
            if (lc < (unsigned)CH && h2bits(r) != 0u)
                atom_add_h2(&acc2[lc], r, 0);
        }
    }

    __syncthreads();
    __half2* row = partial12 + ((size_t)cr * S2 + s) * CH;
    for (int i = threadIdx.x; i < CH; i += BLK2) row[i] = acc2[i];
}

// out[a] = q[a]*sum(v) + dip[a]*sum(w); chunk 0 sums S1 rows of partial0,
// chunk c>=1 sums S2 rows of partial12[c-1]. 4 waves split the rows.
__global__ __launch_bounds__(256) void pc_reduce_vw2(
    const __half2* __restrict__ partial0,
    const __half2* __restrict__ partial12,
    const float*   __restrict__ q,
    const float*   __restrict__ dip,
    float*         __restrict__ out,
    int n_atoms, int CH, int S1, int S2)
{
    __shared__ float2 sh[256];
    int a0   = blockIdx.x * 64;
    int lane = threadIdx.x & 63;
    int w    = threadIdx.x >> 6;
    int a    = a0 + lane;

    float sv = 0.0f, sw = 0.0f;
    if (a < n_atoms) {
        int c = a / CH;
        const __half2* p;
        int S, col;
        if (c == 0) { p = partial0; S = S1; col = a; }
        else {
            p = partial12 + (size_t)(c - 1) * S2 * CH;
            S = S2; col = a - c * CH;
        }
        int per = S >> 2;                  // S % 4 == 0
        int s = w * per, send = s + per;
        for (; s < send; ++s) {
            float2 t = __half22float2(p[(size_t)s * CH + col]);
            sv += t.x; sw += t.y;
        }
    }
    sh[threadIdx.x] = make_float2(sv, sw);
    __syncthreads();
    if (w == 0 && a < n_atoms) {
        float2 t0 = sh[lane],       t1 = sh[64 + lane];
        float2 t2 = sh[128 + lane], t3 = sh[192 + lane];
        float fv = (t0.x + t1.x) + (t2.x + t3.x);
        float fw = (t0.y + t1.y) + (t2.y + t3.y);
        out[a] = fmaf(q[a], fv, dip[a] * fw);
    }
}

// Full-precision global-atomic fallback (LDS probe failure / tiny ws).
__global__ __launch_bounds__(256) void pc_dipole_edges_atomic(
    const float* __restrict__ q,
    const float* __restrict__ dip,
    const float* __restrict__ dist,
    const int*   __restrict__ idx_i,
    const int*   __restrict__ idx_j,
    float*       __restrict__ out,
    int n_edges)
{
    int t = blockIdx.x * blockDim.x + threadIdx.x;
    const int stride = gridDim.x * blockDim.x;
    for (int e = t; e < n_edges; e += stride) {
        float d = dist[e];
        if (d > CUTOFF_C) continue;
        int i = idx_i[e], j = idx_j[e];
        atomicAdd(&out[i], edge_energy(d, q[i], q[j], dip[i], dip[j]));
    }
}

static bool probe_lds(const void* f, int blk, size_t lds) {
    hipError_t e1 = hipFuncSetAttribute(
        f, hipFuncAttributeMaxDynamicSharedMemorySize, (int)lds);
    int nb = 0;
    hipError_t e2 = hipOccupancyMaxActiveBlocksPerMultiprocessor(&nb, f, blk, lds);
    return (e1 == hipSuccess && e2 == hipSuccess && nb >= 1);
}

extern "C" void kernel_launch(void* const* d_in, const int* in_sizes, int n_in,
                              void* d_out, int out_size, void* d_ws, size_t ws_size,
                              hipStream_t stream) {
    const float* q     = (const float*)d_in[0];
    const float* dip   = (const float*)d_in[1];
    const float* dist  = (const float*)d_in[2];
    const int*   idx_i = (const int*)d_in[3];
    const int*   idx_j = (const int*)d_in[4];
    float*       out   = (float*)d_out;

    int n_edges = in_sizes[2];
    int n_atoms = out_size;
    int n4      = n_edges >> 2;

    const int CH  = CH_T0;
    size_t    lds = (size_t)CH * sizeof(__half2);   // 132 KB

    int nch   = (n_atoms + CH - 1) / CH;            // 3 for 100K atoms
    int nrest = nch - 1;
    int S2    = 0;
    if (nrest > 0) {
        S2 = (256 / nrest) & ~3;                    // 128 for nrest=2
        if (S2 < 4) S2 = 4;
    }

    bool ok1 = probe_lds((const void*)&pc_produce_scatter0<CH_T0>, BLK1, lds);
    bool ok2 = (nrest == 0) ||
               probe_lds((const void*)&pc_scatter_rest<CH_T0>, BLK2, lds);

    // Workspace: [qd half2][vw half2 n_edges][partial0 S1*CH][partial12 nrest*S2*CH]
    size_t qd_b  = ((size_t)n_atoms * sizeof(__half2) + 255) & ~(size_t)255;
    size_t vw_b  = ((size_t)n_edges * sizeof(__half2) + 255) & ~(size_t)255;
    size_t p0_b  = ((size_t)S1_N * CH * sizeof(__half2) + 255) & ~(size_t)255;
    size_t p12_b = (size_t)nrest * S2 * CH * sizeof(__half2);
    size_t need  = qd_b + vw_b + p0_b + p12_b;

    if (ok1 && ok2 && need <= ws_size && n_atoms > 0) {
        __half2* qd  = (__half2*)d_ws;
        __half2* vw  = (__half2*)((char*)d_ws + qd_b);
        __half2* p0  = (__half2*)((char*)d_ws + qd_b + vw_b);
        __half2* p12 = (__half2*)((char*)d_ws + qd_b + vw_b + p0_b);

        int gps1 = (n4 + S1_N - 1) / S1_N;

        pc_pack_qd_h<<<(n_atoms + 255) / 256, 256, 0, stream>>>(q, dip, qd,
                                                                n_atoms);
        pc_produce_scatter0<CH_T0><<<S1_N, BLK1, lds, stream>>>(
            dist, idx_i, idx_j, qd, vw, p0, n_edges, n4, S1_N, gps1);
        if (nrest > 0) {
            int gps2 = (n4 + S2 - 1) / S2;
            pc_scatter_rest<CH_T0><<<S2 * nrest, BLK2, lds, stream>>>(
                idx_i, vw, p12, n_edges, n4, S2, gps2, nrest);
        }
        pc_reduce_vw2<<<(n_atoms + 63) / 64, 256, 0, stream>>>(
            p0, p12, q, dip, out, n_atoms, CH, S1_N, S2);
    } else {
        hipMemsetAsync(out, 0, (size_t)n_atoms * sizeof(float), stream);
        int grid = (n_edges + 255) / 256;
        pc_dipole_edges_atomic<<<grid, 256, 0, stream>>>(
            q, dip, dist, idx_i, idx_j, out, n_edges);
    }
}

// Round 12
// 164.854 us; speedup vs baseline: 1.1688x; 1.1688x over previous
//
#include <hip/hip_runtime.h>
#include <hip/hip_bf16.h>
#include <hip/hip_fp16.h>

// Problem constants (match reference)
#define CUTOFF_C    12.0f
#define CUTOFF_SR_C 2.0f
#define CUTOFF_SQ_C 144.0f
#define KEHALF_C    7.199822675975274f

#define CH_T0  33792      // chunk atoms: 132 KB half2 accumulator
#define LUTN   2048       // radial-factor LUT bins over [0, CUTOFF]
#define BLK1   1024

__device__ __forceinline__ float edge_energy(float d, float qi, float qj,
                                             float di, float dj) {
    float inv_d   = __frcp_rn(d);
    float dsh     = __fsqrt_rn(fmaf(d, d, 1.0f));
    float inv_dsh = __frcp_rn(dsh);
    float x  = d * (1.0f / CUTOFF_SR_C);
    float x3 = x * x * x;
    float sw = fmaf(x3, fmaf(x, fmaf(x, -6.0f, 15.0f), -10.0f), 1.0f);
    float sw_off = (d < CUTOFF_SR_C) ? sw : 0.0f;
    float Eoq = inv_d   + fmaf(d,   (1.0f / CUTOFF_SQ_C), -(2.0f / CUTOFF_C));
    float Esq = inv_dsh + fmaf(dsh, (1.0f / CUTOFF_SQ_C), -(2.0f / CUTOFF_C));
    float Eq  = (KEHALF_C * qi * qj) * fmaf(sw_off, Esq - Eoq, Eoq);
    float Eod = inv_d * inv_d * inv_d;
    float Esd = inv_dsh * inv_dsh * inv_dsh;
    float Ed  = (KEHALF_C * di * dj) * fmaf(sw_off, Esd - Eod, Eod);
    return Eq + Ed;
}

// Exact radial factors (KEHALF folded): v = qj*F, w = dj*G.
__device__ __forceinline__ float2 fg_exact(float d) {
    float inv_d   = 1.0f / d;
    float dsh     = sqrtf(fmaf(d, d, 1.0f));
    float inv_dsh = 1.0f / dsh;
    float x  = d * (1.0f / CUTOFF_SR_C);
    float x3 = x * x * x;
    float sw = fmaf(x3, fmaf(x, fmaf(x, -6.0f, 15.0f), -10.0f), 1.0f);
    float sw_off = (d < CUTOFF_SR_C) ? sw : 0.0f;
    float Foq = inv_d   + fmaf(d,   (1.0f / CUTOFF_SQ_C), -(2.0f / CUTOFF_C));
    float Fsq = inv_dsh + fmaf(dsh, (1.0f / CUTOFF_SQ_C), -(2.0f / CUTOFF_C));
    float F   = fmaf(sw_off, Fsq - Foq, Foq);
    float God = inv_d * inv_d * inv_d;
    float Gsd = inv_dsh * inv_dsh * inv_dsh;
    float G   = fmaf(sw_off, Gsd - God, God);
    return make_float2(KEHALF_C * F, KEHALF_C * G);
}

__device__ __forceinline__ __half2 vw_make_exact(float d, __half2 hqdj) {
    float2 qdj = __half22float2(hqdj);
    float2 fg  = fg_exact(d);
    return __floats2half2_rn(qdj.x * fg.x, qdj.y * fg.y);
}

__device__ __forceinline__ unsigned h2bits(__half2 h) {
    union { __half2 h; unsigned u; } c; c.h = h; return c.u;
}
__device__ __forceinline__ __half2 bits2h(unsigned u) {
    union { unsigned u; __half2 h; } c; c.u = u; return c.h;
}
// half2 atomic add: HW atomicAdd(__half2*) (ds_pk_add_f16) if available,
// else CAS fallback.
template <typename T>
__device__ __forceinline__ auto atom_add_h2(T* p, T v, int)
    -> decltype(atomicAdd(p, v), void()) {
    atomicAdd(p, v);
}
template <typename T>
__device__ __forceinline__ void atom_add_h2(T* p, T v, long) {
    unsigned* u = (unsigned*)p;
    unsigned old = *u, assumed;
    do {
        assumed = old;
        __half2 sum = __hadd2(bits2h(assumed), v);
        old = atomicCAS(u, assumed, h2bits(sum));
    } while (old != assumed);
}

// Pack {q, dip} -> half2 (4 B / atom), j-side gather table.
__global__ __launch_bounds__(256) void pc_pack_qd_h(
    const float* __restrict__ q,
    const float* __restrict__ dip,
    __half2*     __restrict__ qd,
    int n_atoms)
{
    int a = blockIdx.x * 256 + threadIdx.x;
    if (a < n_atoms) qd[a] = __floats2half2_rn(q[a], dip[a]);
}

// Fused compute+scatter with in-LDS radial LUT.
// Block b: s = b % S (slice), c = b / S (chunk). Same-slice blocks are S
// apart; S % 8 == 0 makes them land on the same XCD under round-robin
// dispatch, sharing the tri-stream in that XCD's L2 (perf heuristic only).
// Survivor body: 2 ds_read_b64 (LUT lerp) + ~10 VALU — replaces the 3x
// replicated transcendental body that measured VALUBusy=43%.
template <int CH, int BLK>
__global__ __launch_bounds__(BLK) void pc_scatter_lut(
    const float*   __restrict__ dist,
    const int*     __restrict__ idx_i,
    const int*     __restrict__ idx_j,
    const __half2* __restrict__ qd,
    __half2*       __restrict__ partial,   // [S][n_atoms] half2 {sumv,sumw}
    int n_edges, int n4, int S, int gps, int n_atoms, int nch)
{
    extern __shared__ char smem[];
    __half2* acc2 = (__half2*)smem;                              // CH half2
    float2*  lut  = (float2*)(smem + (size_t)CH * sizeof(__half2)); // LUTN+1

    const int s    = blockIdx.x % S;
    const int c    = blockIdx.x / S;
    const int base = c * CH;
    const int lim  = min(CH, n_atoms - base);

    const __half2 hzero = __floats2half2_rn(0.0f, 0.0f);
    for (int i = threadIdx.x; i < CH; i += BLK) acc2[i] = hzero;

    // Build LUT: F,G at d_k = k * CUTOFF/LUTN (KEHALF folded). d>=0.5 in
    // the data, so low bins are never read; clamp avoids inf anyway.
    const float hstep = CUTOFF_C / (float)LUTN;
    for (int k = threadIdx.x; k <= LUTN; k += BLK) {
        float d = fmaxf((float)k * hstep, 0.25f * hstep);
        lut[k] = fg_exact(d);
    }
    __syncthreads();

    const int g0 = s * gps;
    const int g1 = min(g0 + gps, n4);
    const int4*   idxi4 = (const int4*)idx_i;
    const int4*   idxj4 = (const int4*)idx_j;
    const float4* dist4 = (const float4*)dist;
    const float   dscale = (float)LUTN / CUTOFF_C;

    for (int g = g0 + (int)threadIdx.x; g < g1; g += BLK) {
        int4   i4 = idxi4[g];
        int4   j4 = idxj4[g];
        float4 d4 = dist4[g];

        int      ii[4] = { i4.x, i4.y, i4.z, i4.w };
        int      jj[4] = { j4.x, j4.y, j4.z, j4.w };
        float    dd[4] = { d4.x, d4.y, d4.z, d4.w };
        unsigned lc[4];
        bool     vl[4];
        __half2  qh[4];

        #pragma unroll
        for (int k = 0; k < 4; ++k) {
            lc[k] = (unsigned)(ii[k] - base);
            vl[k] = (lc[k] < (unsigned)CH) && (dd[k] <= CUTOFF_C);
        }
        // all gathers in flight before first use
        #pragma unroll
        for (int k = 0; k < 4; ++k)
            qh[k] = vl[k] ? qd[jj[k]] : hzero;

        #pragma unroll
        for (int k = 0; k < 4; ++k) {
            if (vl[k]) {
                float t  = dd[k] * dscale;
                int   kk = min((int)t, LUTN - 1);
                float fr = t - (float)kk;
                float2 l0 = lut[kk];
                float2 l1 = lut[kk + 1];
                float F = fmaf(fr, l1.x - l0.x, l0.x);
                float G = fmaf(fr, l1.y - l0.y, l0.y);
                float2 qdj = __half22float2(qh[k]);
                __half2 vw = __floats2half2_rn(qdj.x * F, qdj.y * G);
                atom_add_h2(&acc2[lc[k]], vw, 0);
            }
        }
    }

    if (s == S - 1) {  // scalar tail (n_edges % 4)
        for (int e = (n4 << 2) + (int)threadIdx.x; e < n_edges; e += BLK) {
            int i = idx_i[e];
            float d = dist[e];
            unsigned local = (unsigned)(i - base);
            if (local < (unsigned)CH && d <= CUTOFF_C) {
                __half2 vw = vw_make_exact(d, qd[idx_j[e]]);
                atom_add_h2(&acc2[local], vw, 0);
            }
        }
    }

    __syncthreads();
    __half2* row = partial + (size_t)s * n_atoms + base;
    for (int i = threadIdx.x; i < lim; i += BLK) row[i] = acc2[i];
}

// Round-10 exact fused kernel (fallback tier if the LUT LDS probe fails).
template <int CH, int BLK>
__global__ __launch_bounds__(BLK) void pc_scatter_fused(
    const float*   __restrict__ dist,
    const int*     __restrict__ idx_i,
    const int*     __restrict__ idx_j,
    const __half2* __restrict__ qd,
    __half2*       __restrict__ partial,
    int n_edges, int n4, int S, int gps, int n_atoms, int nch)
{
    extern __shared__ __half2 accf[];

    const int s    = blockIdx.x % S;
    const int c    = blockIdx.x / S;
    const int base = c * CH;
    const int lim  = min(CH, n_atoms - base);

    const __half2 hzero = __floats2half2_rn(0.0f, 0.0f);
    for (int i = threadIdx.x; i < CH; i += BLK) accf[i] = hzero;
    __syncthreads();

    const int g0 = s * gps;
    const int g1 = min(g0 + gps, n4);
    const int4*   idxi4 = (const int4*)idx_i;
    const int4*   idxj4 = (const int4*)idx_j;
    const float4* dist4 = (const float4*)dist;

    for (int g = g0 + (int)threadIdx.x; g < g1; g += BLK) {
        int4   i4 = idxi4[g];
        int4   j4 = idxj4[g];
        float4 d4 = dist4[g];
        int      ii[4] = { i4.x, i4.y, i4.z, i4.w };
        int      jj[4] = { j4.x, j4.y, j4.z, j4.w };
        float    dd[4] = { d4.x, d4.y, d4.z, d4.w };
        unsigned lc[4];
        bool     vl[4];
        __half2  qh[4];
        #pragma unroll
        for (int k = 0; k < 4; ++k) {
            lc[k] = (unsigned)(ii[k] - base);
            vl[k] = (lc[k] < (unsigned)CH) && (dd[k] <= CUTOFF_C);
        }
        #pragma unroll
        for (int k = 0; k < 4; ++k)
            qh[k] = vl[k] ? qd[jj[k]] : hzero;
        #pragma unroll
        for (int k = 0; k < 4; ++k) {
            if (vl[k])
                atom_add_h2(&accf[lc[k]], vw_make_exact(dd[k], qh[k]), 0);
        }
    }

    if (s == S - 1) {
        for (int e = (n4 << 2) + (int)threadIdx.x; e < n_edges; e += BLK) {
            int i = idx_i[e];
            float d = dist[e];
            unsigned local = (unsigned)(i - base);
            if (local < (unsigned)CH && d <= CUTOFF_C)
                atom_add_h2(&accf[local], vw_make_exact(d, qd[idx_j[e]]), 0);
        }
    }

    __syncthreads();
    __half2* row = partial + (size_t)s * n_atoms + base;
    for (int i = threadIdx.x; i < lim; i += BLK) row[i] = accf[i];
}

// out[a] = q[a]*sum_s(v) + dip[a]*sum_s(w) — exact fp32 recombination.
__global__ __launch_bounds__(256) void pc_reduce_vw(
    const __half2* __restrict__ partial,   // [S][n_atoms]
    const float*   __restrict__ q,
    const float*   __restrict__ dip,
    float*         __restrict__ out,
    int n_atoms, int S)
{
    __shared__ float2 sh[256];
    int a0   = blockIdx.x * 64;
    int lane = threadIdx.x & 63;
    int w    = threadIdx.x >> 6;
    int a    = a0 + lane;

    float sv = 0.0f, sw = 0.0f;
    if (a < n_atoms) {
        int per = S >> 2;                  // S % 4 == 0
        const __half2* p = partial + a;
        int s = w * per, send = s + per;
        for (; s < send; ++s) {
            float2 t = __half22float2(p[(size_t)s * n_atoms]);
            sv += t.x; sw += t.y;
        }
    }
    sh[threadIdx.x] = make_float2(sv, sw);
    __syncthreads();
    if (w == 0 && a < n_atoms) {
        float2 t0 = sh[lane],       t1 = sh[64 + lane];
        float2 t2 = sh[128 + lane], t3 = sh[192 + lane];
        float fv = (t0.x + t1.x) + (t2.x + t3.x);
        float fw = (t0.y + t1.y) + (t2.y + t3.y);
        out[a] = fmaf(q[a], fv, dip[a] * fw);
    }
}

// Full-precision global-atomic fallback (probe failure / tiny ws).
__global__ __launch_bounds__(256) void pc_dipole_edges_atomic(
    const float* __restrict__ q,
    const float* __restrict__ dip,
    const float* __restrict__ dist,
    const int*   __restrict__ idx_i,
    const int*   __restrict__ idx_j,
    float*       __restrict__ out,
    int n_edges)
{
    int t = blockIdx.x * blockDim.x + threadIdx.x;
    const int stride = gridDim.x * blockDim.x;
    for (int e = t; e < n_edges; e += stride) {
        float d = dist[e];
        if (d > CUTOFF_C) continue;
        int i = idx_i[e], j = idx_j[e];
        atomicAdd(&out[i], edge_energy(d, q[i], q[j], dip[i], dip[j]));
    }
}

static bool probe_lds(const void* f, int blk, size_t lds) {
    hipError_t e1 = hipFuncSetAttribute(
        f, hipFuncAttributeMaxDynamicSharedMemorySize, (int)lds);
    int nb = 0;
    hipError_t e2 = hipOccupancyMaxActiveBlocksPerMultiprocessor(&nb, f, blk, lds);
    return (e1 == hipSuccess && e2 == hipSuccess && nb >= 1);
}

extern "C" void kernel_launch(void* const* d_in, const int* in_sizes, int n_in,
                              void* d_out, int out_size, void* d_ws, size_t ws_size,
                              hipStream_t stream) {
    const float* q     = (const float*)d_in[0];
    const float* dip   = (const float*)d_in[1];
    const float* dist  = (const float*)d_in[2];
    const int*   idx_i = (const int*)d_in[3];
    const int*   idx_j = (const int*)d_in[4];
    float*       out   = (float*)d_out;

    int n_edges = in_sizes[2];
    int n_atoms = out_size;
    int n4      = n_edges >> 2;

    const int CH = CH_T0;
    int nch = (n_atoms + CH - 1) / CH;               // 3 for 100K atoms

    // S: multiple of 8 (same-XCD slice swizzle) and of 4 (reduce), with
    // S * nch <= 256 (tail-free grid). nch=3 -> S=80, grid=240.
    int S = (256 / nch) & ~7;
    if (S < 8) S = 8;

    size_t lds_lut = (size_t)CH * sizeof(__half2)
                   + (size_t)(LUTN + 1) * sizeof(float2);   // ~148 KB
    size_t lds_fus = (size_t)CH * sizeof(__half2);          // 132 KB

    bool ok_lut = probe_lds((const void*)&pc_scatter_lut<CH_T0, BLK1>,
                            BLK1, lds_lut);
    bool ok_fus = ok_lut ||
                  probe_lds((const void*)&pc_scatter_fused<CH_T0, BLK1>,
                            BLK1, lds_fus);

    // Workspace: [qd half2][partial S*n_atoms half2]
    size_t qd_b  = ((size_t)n_atoms * sizeof(__half2) + 255) & ~(size_t)255;
    size_t avail = (ws_size > qd_b) ? ws_size - qd_b : 0;
    int S_fit = (int)(avail / ((size_t)n_atoms * sizeof(__half2)));
    if (S_fit < S) S = S_fit & ~7;

    if ((ok_lut || ok_fus) && S >= 8 && n_atoms > 0) {
        __half2* qd      = (__half2*)d_ws;
        __half2* partial = (__half2*)((char*)d_ws + qd_b);
        int      gps     = (n4 + S - 1) / S;

        pc_pack_qd_h<<<(n_atoms + 255) / 256, 256, 0, stream>>>(q, dip, qd,
                                                                n_atoms);
        if (ok_lut)
            pc_scatter_lut<CH_T0, BLK1><<<S * nch, BLK1, lds_lut, stream>>>(
                dist, idx_i, idx_j, qd, partial, n_edges, n4, S, gps,
                n_atoms, nch);
        else
            pc_scatter_fused<CH_T0, BLK1><<<S * nch, BLK1, lds_fus, stream>>>(
                dist, idx_i, idx_j, qd, partial, n_edges, n4, S, gps,
                n_atoms, nch);
        pc_reduce_vw<<<(n_atoms + 63) / 64, 256, 0, stream>>>(
            partial, q, dip, out, n_atoms, S);
    } else {
        hipMemsetAsync(out, 0, (size_t)n_atoms * sizeof(float), stream);
        int grid = (n_edges + 255) / 256;
        pc_dipole_edges_atomic<<<grid, 256, 0, stream>>>(
            q, dip, dist, idx_i, idx_j, out, n_edges);
    }
}

// Round 13
// 163.116 us; speedup vs baseline: 1.1813x; 1.0107x over previous
//
#include <hip/hip_runtime.h>
#include <hip/hip_bf16.h>
#include <hip/hip_fp16.h>

// Problem constants (match reference)
#define CUTOFF_C    12.0f
#define CUTOFF_SR_C 2.0f
#define CUTOFF_SQ_C 144.0f
#define KEHALF_C    7.199822675975274f

#define BLK1   1024

// Duo config: 2 blocks/CU (32 waves/CU). 17408*4 + 1025*8 = 77832 B <= 80 KB.
#define CH_DUO   17408
#define LUT_DUO  1024
// Solo config (round-12 fallback): 1 block/CU.
#define CH_SOLO  33792
#define LUT_SOLO 2048

__device__ __forceinline__ float edge_energy(float d, float qi, float qj,
                                             float di, float dj) {
    float inv_d   = __frcp_rn(d);
    float dsh     = __fsqrt_rn(fmaf(d, d, 1.0f));
    float inv_dsh = __frcp_rn(dsh);
    float x  = d * (1.0f / CUTOFF_SR_C);
    float x3 = x * x * x;
    float sw = fmaf(x3, fmaf(x, fmaf(x, -6.0f, 15.0f), -10.0f), 1.0f);
    float sw_off = (d < CUTOFF_SR_C) ? sw : 0.0f;
    float Eoq = inv_d   + fmaf(d,   (1.0f / CUTOFF_SQ_C), -(2.0f / CUTOFF_C));
    float Esq = inv_dsh + fmaf(dsh, (1.0f / CUTOFF_SQ_C), -(2.0f / CUTOFF_C));
    float Eq  = (KEHALF_C * qi * qj) * fmaf(sw_off, Esq - Eoq, Eoq);
    float Eod = inv_d * inv_d * inv_d;
    float Esd = inv_dsh * inv_dsh * inv_dsh;
    float Ed  = (KEHALF_C * di * dj) * fmaf(sw_off, Esd - Eod, Eod);
    return Eq + Ed;
}

// Exact radial factors (KEHALF folded): v = qj*F, w = dj*G.
__device__ __forceinline__ float2 fg_exact(float d) {
    float inv_d   = 1.0f / d;
    float dsh     = sqrtf(fmaf(d, d, 1.0f));
    float inv_dsh = 1.0f / dsh;
    float x  = d * (1.0f / CUTOFF_SR_C);
    float x3 = x * x * x;
    float sw = fmaf(x3, fmaf(x, fmaf(x, -6.0f, 15.0f), -10.0f), 1.0f);
    float sw_off = (d < CUTOFF_SR_C) ? sw : 0.0f;
    float Foq = inv_d   + fmaf(d,   (1.0f / CUTOFF_SQ_C), -(2.0f / CUTOFF_C));
    float Fsq = inv_dsh + fmaf(dsh, (1.0f / CUTOFF_SQ_C), -(2.0f / CUTOFF_C));
    float F   = fmaf(sw_off, Fsq - Foq, Foq);
    float God = inv_d * inv_d * inv_d;
    float Gsd = inv_dsh * inv_dsh * inv_dsh;
    float G   = fmaf(sw_off, Gsd - God, God);
    return make_float2(KEHALF_C * F, KEHALF_C * G);
}

__device__ __forceinline__ __half2 vw_make_exact(float d, __half2 hqdj) {
    float2 qdj = __half22float2(hqdj);
    float2 fg  = fg_exact(d);
    return __floats2half2_rn(qdj.x * fg.x, qdj.y * fg.y);
}

__device__ __forceinline__ unsigned h2bits(__half2 h) {
    union { __half2 h; unsigned u; } c; c.h = h; return c.u;
}
__device__ __forceinline__ __half2 bits2h(unsigned u) {
    union { unsigned u; __half2 h; } c; c.u = u; return c.h;
}
// half2 atomic add: HW atomicAdd(__half2*) (ds_pk_add_f16) if available.
template <typename T>
__device__ __forceinline__ auto atom_add_h2(T* p, T v, int)
    -> decltype(atomicAdd(p, v), void()) {
    atomicAdd(p, v);
}
template <typename T>
__device__ __forceinline__ void atom_add_h2(T* p, T v, long) {
    unsigned* u = (unsigned*)p;
    unsigned old = *u, assumed;
    do {
        assumed = old;
        __half2 sum = __hadd2(bits2h(assumed), v);
        old = atomicCAS(u, assumed, h2bits(sum));
    } while (old != assumed);
}

// Pack {q, dip} -> half2 (4 B / atom), j-side gather table.
__global__ __launch_bounds__(256) void pc_pack_qd_h(
    const float* __restrict__ q,
    const float* __restrict__ dip,
    __half2*     __restrict__ qd,
    int n_atoms)
{
    int a = blockIdx.x * 256 + threadIdx.x;
    if (a < n_atoms) qd[a] = __floats2half2_rn(q[a], dip[a]);
}

// Fused compute+scatter with in-LDS radial LUT.
// Block b: s = b % S (slice), c = b / S (chunk). S % 8 == 0 keeps same-slice
// blocks on one XCD (L2 shares the tri-stream; FETCH 114->39 MB measured).
// DUO config: 2 blocks/CU -> 32 waves/CU (latency-hiding experiment).
template <int CH, int LUTN, int BLK>
__global__ __launch_bounds__(BLK) void pc_scatter_lut(
    const float*   __restrict__ dist,
    const int*     __restrict__ idx_i,
    const int*     __restrict__ idx_j,
    const __half2* __restrict__ qd,
    __half2*       __restrict__ partial,   // [S][n_atoms] half2 {sumv,sumw}
    int n_edges, int n4, int S, int gps, int n_atoms, int nch)
{
    extern __shared__ char smem[];
    __half2* acc2 = (__half2*)smem;                                  // CH
    float2*  lut  = (float2*)(smem + (size_t)CH * sizeof(__half2));  // LUTN+1

    const int s    = blockIdx.x % S;
    const int c    = blockIdx.x / S;
    const int base = c * CH;
    const int lim  = min(CH, n_atoms - base);

    const __half2 hzero = __floats2half2_rn(0.0f, 0.0f);
    for (int i = threadIdx.x; i < CH; i += BLK) acc2[i] = hzero;

    const float hstep = CUTOFF_C / (float)LUTN;
    for (int k = threadIdx.x; k <= LUTN; k += BLK) {
        float d = fmaxf((float)k * hstep, 0.25f * hstep);
        lut[k] = fg_exact(d);
    }
    __syncthreads();

    const int g0 = s * gps;
    const int g1 = min(g0 + gps, n4);
    const int4*   idxi4 = (const int4*)idx_i;
    const int4*   idxj4 = (const int4*)idx_j;
    const float4* dist4 = (const float4*)dist;
    const float   dscale = (float)LUTN / CUTOFF_C;

    for (int g = g0 + (int)threadIdx.x; g < g1; g += BLK) {
        int4   i4 = idxi4[g];
        int4   j4 = idxj4[g];
        float4 d4 = dist4[g];

        int      ii[4] = { i4.x, i4.y, i4.z, i4.w };
        int      jj[4] = { j4.x, j4.y, j4.z, j4.w };
        float    dd[4] = { d4.x, d4.y, d4.z, d4.w };
        unsigned lc[4];
        bool     vl[4];
        __half2  qh[4];

        #pragma unroll
        for (int k = 0; k < 4; ++k) {
            lc[k] = (unsigned)(ii[k] - base);
            vl[k] = (lc[k] < (unsigned)CH) && (dd[k] <= CUTOFF_C);
        }
        #pragma unroll
        for (int k = 0; k < 4; ++k)
            qh[k] = vl[k] ? qd[jj[k]] : hzero;

        #pragma unroll
        for (int k = 0; k < 4; ++k) {
            if (vl[k]) {
                float t  = dd[k] * dscale;
                int   kk = min((int)t, LUTN - 1);
                float fr = t - (float)kk;
                float2 l0 = lut[kk];
                float2 l1 = lut[kk + 1];
                float F = fmaf(fr, l1.x - l0.x, l0.x);
                float G = fmaf(fr, l1.y - l0.y, l0.y);
                float2 qdj = __half22float2(qh[k]);
                __half2 vw = __floats2half2_rn(qdj.x * F, qdj.y * G);
                atom_add_h2(&acc2[lc[k]], vw, 0);
            }
        }
    }

    if (s == S - 1) {  // scalar tail (n_edges % 4)
        for (int e = (n4 << 2) + (int)threadIdx.x; e < n_edges; e += BLK) {
            int i = idx_i[e];
            float d = dist[e];
            unsigned local = (unsigned)(i - base);
            if (local < (unsigned)CH && d <= CUTOFF_C) {
                __half2 vw = vw_make_exact(d, qd[idx_j[e]]);
                atom_add_h2(&acc2[local], vw, 0);
            }
        }
    }

    __syncthreads();
    __half2* row = partial + (size_t)s * n_atoms + base;
    for (int i = threadIdx.x; i < lim; i += BLK) row[i] = acc2[i];
}

// out[a] = q[a]*sum_s(v) + dip[a]*sum_s(w) — exact fp32 recombination.
__global__ __launch_bounds__(256) void pc_reduce_vw(
    const __half2* __restrict__ partial,   // [S][n_atoms]
    const float*   __restrict__ q,
    const float*   __restrict__ dip,
    float*         __restrict__ out,
    int n_atoms, int S)
{
    __shared__ float2 sh[256];
    int a0   = blockIdx.x * 64;
    int lane = threadIdx.x & 63;
    int w    = threadIdx.x >> 6;
    int a    = a0 + lane;

    float sv = 0.0f, sw = 0.0f;
    if (a < n_atoms) {
        int per = S >> 2;                  // S % 4 == 0
        const __half2* p = partial + a;
        int s = w * per, send = s + per;
        for (; s < send; ++s) {
            float2 t = __half22float2(p[(size_t)s * n_atoms]);
            sv += t.x; sw += t.y;
        }
    }
    sh[threadIdx.x] = make_float2(sv, sw);
    __syncthreads();
    if (w == 0 && a < n_atoms) {
        float2 t0 = sh[lane],       t1 = sh[64 + lane];
        float2 t2 = sh[128 + lane], t3 = sh[192 + lane];
        float fv = (t0.x + t1.x) + (t2.x + t3.x);
        float fw = (t0.y + t1.y) + (t2.y + t3.y);
        out[a] = fmaf(q[a], fv, dip[a] * fw);
    }
}

// Full-precision global-atomic fallback (probe failure / tiny ws).
__global__ __launch_bounds__(256) void pc_dipole_edges_atomic(
    const float* __restrict__ q,
    const float* __restrict__ dip,
    const float* __restrict__ dist,
    const int*   __restrict__ idx_i,
    const int*   __restrict__ idx_j,
    float*       __restrict__ out,
    int n_edges)
{
    int t = blockIdx.x * blockDim.x + threadIdx.x;
    const int stride = gridDim.x * blockDim.x;
    for (int e = t; e < n_edges; e += stride) {
        float d = dist[e];
        if (d > CUTOFF_C) continue;
        int i = idx_i[e], j = idx_j[e];
        atomicAdd(&out[i], edge_energy(d, q[i], q[j], dip[i], dip[j]));
    }
}

static int probe_blocks(const void* f, int blk, size_t lds) {
    hipError_t e1 = hipFuncSetAttribute(
        f, hipFuncAttributeMaxDynamicSharedMemorySize, (int)lds);
    int nb = 0;
    hipError_t e2 = hipOccupancyMaxActiveBlocksPerMultiprocessor(&nb, f, blk, lds);
    if (e1 != hipSuccess || e2 != hipSuccess) return 0;
    return nb;
}

extern "C" void kernel_launch(void* const* d_in, const int* in_sizes, int n_in,
                              void* d_out, int out_size, void* d_ws, size_t ws_size,
                              hipStream_t stream) {
    const float* q     = (const float*)d_in[0];
    const float* dip   = (const float*)d_in[1];
    const float* dist  = (const float*)d_in[2];
    const int*   idx_i = (const int*)d_in[3];
    const int*   idx_j = (const int*)d_in[4];
    float*       out   = (float*)d_out;

    int n_edges = in_sizes[2];
    int n_atoms = out_size;
    int n4      = n_edges >> 2;

    // --- config select: duo (2 blocks/CU, 32 waves/CU) preferred ---
    size_t lds_duo  = (size_t)CH_DUO  * sizeof(__half2)
                    + (size_t)(LUT_DUO  + 1) * sizeof(float2);  // 77832 B
    size_t lds_solo = (size_t)CH_SOLO * sizeof(__half2)
                    + (size_t)(LUT_SOLO + 1) * sizeof(float2);  // ~148 KB

    int nb_duo = probe_blocks((const void*)&pc_scatter_lut<CH_DUO, LUT_DUO, BLK1>,
                              BLK1, lds_duo);
    int nb_solo = probe_blocks((const void*)&pc_scatter_lut<CH_SOLO, LUT_SOLO, BLK1>,
                               BLK1, lds_solo);

    bool use_duo = (nb_duo >= 2);
    int  CH, nch, S, cap;
    size_t lds;
    if (use_duo) {
        CH  = CH_DUO;  lds = lds_duo;
        nch = (n_atoms + CH - 1) / CH;               // 6 for 100K
        cap = 512;                                   // 2 blocks/CU * 256
    } else {
        CH  = CH_SOLO; lds = lds_solo;
        nch = (n_atoms + CH - 1) / CH;               // 3 for 100K
        cap = 256;
    }
    S = (cap / nch) & ~7;                            // mult of 8 (XCD swizzle)
    if (S < 8) S = 8;

    // Workspace: [qd half2][partial S*n_atoms half2]
    size_t qd_b  = ((size_t)n_atoms * sizeof(__half2) + 255) & ~(size_t)255;
    size_t avail = (ws_size > qd_b) ? ws_size - qd_b : 0;
    int S_fit = (int)(avail / ((size_t)n_atoms * sizeof(__half2)));
    if (S_fit < S) S = S_fit & ~7;

    bool ok = (use_duo || nb_solo >= 1) && S >= 8 && n_atoms > 0;

    if (ok) {
        __half2* qd      = (__half2*)d_ws;
        __half2* partial = (__half2*)((char*)d_ws + qd_b);
        int      gps     = (n4 + S - 1) / S;

        pc_pack_qd_h<<<(n_atoms + 255) / 256, 256, 0, stream>>>(q, dip, qd,
                                                                n_atoms);
        if (use_duo)
            pc_scatter_lut<CH_DUO, LUT_DUO, BLK1>
                <<<S * nch, BLK1, lds, stream>>>(
                    dist, idx_i, idx_j, qd, partial, n_edges, n4, S, gps,
                    n_atoms, nch);
        else
            pc_scatter_lut<CH_SOLO, LUT_SOLO, BLK1>
                <<<S * nch, BLK1, lds, stream>>>(
                    dist, idx_i, idx_j, qd, partial, n_edges, n4, S, gps,
                    n_atoms, nch);
        pc_reduce_vw<<<(n_atoms + 63) / 64, 256, 0, stream>>>(
            partial, q, dip, out, n_atoms, S);
    } else {
        hipMemsetAsync(out, 0, (size_t)n_atoms * sizeof(float), stream);
        int grid = (n_edges + 255) / 256;
        pc_dipole_edges_atomic<<<grid, 256, 0, stream>>>(
            q, dip, dist, idx_i, idx_j, out, n_edges);
    }
}